// Round 4
// baseline (263.533 us; speedup 1.0000x reference)
//
#include <hip/hip_runtime.h>
#include <hip/hip_bf16.h>

typedef unsigned short u16;
typedef __bf16 bf16x8 __attribute__((ext_vector_type(8)));
typedef float f32x4 __attribute__((ext_vector_type(4)));
typedef unsigned short u16x8 __attribute__((ext_vector_type(8)));
typedef unsigned short u16x4 __attribute__((ext_vector_type(4)));

__device__ __forceinline__ float bf2f(u16 u) {
  unsigned x = ((unsigned)u) << 16;
  return __builtin_bit_cast(float, x);
}
__device__ __forceinline__ u16 f2bf(float f) {
  unsigned u = __builtin_bit_cast(unsigned, f);
  u += 0x7fffu + ((u >> 16) & 1u);
  return (u16)(u >> 16);
}

// async global -> LDS, 16B per lane; lds base is wave-uniform,
// HW scatters at base + lane*16.
__device__ __forceinline__ void gload16(const u16* g, u16* lds) {
  __builtin_amdgcn_global_load_lds(
      (const __attribute__((address_space(1))) void*)g,
      (__attribute__((address_space(3))) void*)lds,
      16, 0, 0);
}

// -------------------------------------------------------------------------
// C[M,N] = A[M,K] * B[N,K]^T, bf16 row-major, strides lda/ldb.
// 128x128 tile, BK=64, 4 waves x (64x64 per wave, 4x4 MFMA 16x16x32).
// LDS: [128][64] u16 rows, eight 16B chunks XOR-swizzled (slot c ^ (g&7))
// -> global_load_lds lane scatter stays contiguous, ds_read_b128 is
// conflict-free (verified R3: SQ_LDS_BANK_CONFLICT 4.2M -> 0).
// Block map: by = (b&7) + 8*(b/(8*NX)) so blocks sharing an A row-panel
// land on the same XCD.  blockIdx.z = split-K chunk (Kc elems each).
// OUT_MODE: 0 = f32 store, 1 = bf16 store (scaled), 2 = f32 atomicAdd.
// -------------------------------------------------------------------------
template <int OUT_MODE, int NX>
__device__ __forceinline__ void gemm_body(
    const u16* __restrict__ A, int lda,
    const u16* __restrict__ B, int ldb,
    void* __restrict__ C, int ldc, int Kc, float cscale)
{
  __shared__ __align__(16) u16 As[128 * 64];
  __shared__ __align__(16) u16 Bs[128 * 64];

  const int b = blockIdx.x;
  const int by = (b & 7) + 8 * (b / (8 * NX));
  const int bx = (b >> 3) % NX;
  const int m0 = by * 128, n0 = bx * 128;
  const int kt0 = blockIdx.z * Kc;

  const int t = threadIdx.x;
  const int w = t >> 6, l = t & 63;
  const int srow = l >> 3;                   // 0..7 within 8-row group
  const int schunk = ((l & 7) ^ srow) * 8;   // swizzled global chunk (elems)
  const int wm = (w >> 1) * 64, wn = (w & 1) * 64;
  const int fr = l & 15;                     // fragment row
  const int q = l >> 4;                      // quarter-wave 0..3

  f32x4 acc[4][4] = {};

  for (int kk = 0; kk < Kc; kk += 64) {
    const int kt = kt0 + kk;
    __syncthreads();
#pragma unroll
    for (int j = 0; j < 4; ++j) {
      const int rr = 8 * (4 * w + j);        // wave-uniform 8-row group base
      gload16(A + (size_t)(m0 + rr + srow) * lda + kt + schunk, As + rr * 64);
      gload16(B + (size_t)(n0 + rr + srow) * ldb + kt + schunk, Bs + rr * 64);
    }
    __syncthreads();

#pragma unroll
    for (int s = 0; s < 2; ++s) {            // two K=32 MFMA steps per tile
      const int j = s * 4 + q;               // global 16B chunk index
      bf16x8 af[4], bfr[4];
#pragma unroll
      for (int i = 0; i < 4; ++i) {
        const int ra = wm + 16 * i + fr;
        af[i] = *(const bf16x8*)(As + ra * 64 + (j ^ (ra & 7)) * 8);
      }
#pragma unroll
      for (int i = 0; i < 4; ++i) {
        const int rb = wn + 16 * i + fr;
        bfr[i] = *(const bf16x8*)(Bs + rb * 64 + (j ^ (rb & 7)) * 8);
      }
#pragma unroll
      for (int i = 0; i < 4; ++i)
#pragma unroll
        for (int jj = 0; jj < 4; ++jj)
          acc[i][jj] = __builtin_amdgcn_mfma_f32_16x16x32_bf16(af[i], bfr[jj], acc[i][jj], 0, 0, 0);
    }
  }

  // C/D layout (m89-verified): col = lane&15, row = (lane>>4)*4 + reg
  const int er = q * 4;
  const int ec = l & 15;
#pragma unroll
  for (int i = 0; i < 4; ++i)
#pragma unroll
    for (int jj = 0; jj < 4; ++jj)
#pragma unroll
      for (int r = 0; r < 4; ++r) {
        const size_t idx = (size_t)(m0 + wm + 16 * i + er + r) * ldc + (n0 + wn + 16 * jj + ec);
        if (OUT_MODE == 1)      ((u16*)C)[idx] = f2bf(acc[i][jj][r] * cscale);
        else if (OUT_MODE == 0) ((float*)C)[idx] = acc[i][jj][r];
        else                    unsafeAtomicAdd(((float*)C) + idx, acc[i][jj][r]);
      }
}

// distinct names per stage so rocprof separates them
__global__ __launch_bounds__(256) void gemm_qkv(const u16* __restrict__ A,
                                                const u16* __restrict__ B,
                                                u16* __restrict__ C) {
  gemm_body<1, 24>(A, 1024, B, 1024, C, 3072, 1024, 1.0f);
}
__global__ __launch_bounds__(256) void gemm_score(const u16* __restrict__ QKV,
                                                  u16* __restrict__ S) {
  // scale 1/sqrt(1024) folded into the epilogue store
  gemm_body<1, 32>(QKV, 3072, QKV + 1024, 3072, S, 4096, 1024, 0.03125f);
}
__global__ __launch_bounds__(256) void gemm_pv(const u16* __restrict__ S,
                                               const u16* __restrict__ Vt,
                                               float* __restrict__ O) {
  // split-K=4 via blockIdx.z, atomic-add epilogue into zeroed O
  gemm_body<2, 8>(S, 4096, Vt, 4096, O, 1024, 1024, 1.0f);
}

// -------------------------------------------------------------------------
// zero-fill d_out (fp32), 1 float4 per thread
// -------------------------------------------------------------------------
__global__ __launch_bounds__(256) void zero_f32(float4* __restrict__ p) {
  p[blockIdx.x * 256 + threadIdx.x] = float4{0.f, 0.f, 0.f, 0.f};
}

// -------------------------------------------------------------------------
// elementwise f32 -> bf16 cast, 4 elems/thread
// -------------------------------------------------------------------------
__global__ __launch_bounds__(256) void cast_f32_bf16(const float* __restrict__ in,
                                                     u16* __restrict__ out) {
  const int i = (blockIdx.x * 256 + threadIdx.x) * 4;
  float4 f = *(const float4*)(in + i);
  u16x4 o;
  o.x = f2bf(f.x); o.y = f2bf(f.y); o.z = f2bf(f.z); o.w = f2bf(f.w);
  *(u16x4*)(out + i) = o;
}

// -------------------------------------------------------------------------
// all three W [1024x1024] f32 -> bf16 transposes in one dispatch (z = which)
// -------------------------------------------------------------------------
__global__ __launch_bounds__(1024) void transpose_w3(
    const float* __restrict__ w0, const float* __restrict__ w1,
    const float* __restrict__ w2, u16* __restrict__ out)
{
  __shared__ u16 tile[32][33];
  const float* in = (blockIdx.z == 0) ? w0 : (blockIdx.z == 1) ? w1 : w2;
  u16* o = out + (size_t)blockIdx.z * 1024 * 1024;
  const int c0 = blockIdx.x * 32, r0 = blockIdx.y * 32;
  const int tx = threadIdx.x, ty = threadIdx.y;
  tile[ty][tx] = f2bf(in[(size_t)(r0 + ty) * 1024 + c0 + tx]);
  __syncthreads();
  o[(size_t)(c0 + ty) * 1024 + r0 + tx] = tile[tx][ty];
}

// -------------------------------------------------------------------------
// bf16 transpose (for V -> V^T): out[c*ldout + r] = in[r*ldin + c]
// -------------------------------------------------------------------------
__global__ __launch_bounds__(1024) void transpose_bf16(
    const u16* __restrict__ in, int ldin, u16* __restrict__ out, int ldout)
{
  __shared__ u16 tile[32][33];
  const int c0 = blockIdx.x * 32, r0 = blockIdx.y * 32;
  const int tx = threadIdx.x, ty = threadIdx.y;
  tile[ty][tx] = in[(size_t)(r0 + ty) * ldin + c0 + tx];
  __syncthreads();
  out[(size_t)(c0 + ty) * ldout + r0 + tx] = tile[tx][ty];
}

// -------------------------------------------------------------------------
// row softmax, in-place on bf16 S[4096][4096] (scale already applied).
// -------------------------------------------------------------------------
__global__ __launch_bounds__(256) void softmax_rows(u16* __restrict__ S) {
  const int N = 4096;
  u16* p = S + (size_t)blockIdx.x * N;
  const int t = threadIdx.x;
  u16x8 u0 = ((const u16x8*)p)[t * 2];
  u16x8 u1 = ((const u16x8*)p)[t * 2 + 1];
  float v[16];
#pragma unroll
  for (int i = 0; i < 8; ++i) v[i] = bf2f(u0[i]);
#pragma unroll
  for (int i = 0; i < 8; ++i) v[8 + i] = bf2f(u1[i]);

  float m = -1e30f;
#pragma unroll
  for (int i = 0; i < 16; ++i) m = fmaxf(m, v[i]);
#pragma unroll
  for (int off = 32; off; off >>= 1) m = fmaxf(m, __shfl_xor(m, off));
  __shared__ float red[8];
  if ((t & 63) == 0) red[t >> 6] = m;
  __syncthreads();
  m = fmaxf(fmaxf(red[0], red[1]), fmaxf(red[2], red[3]));

  float s = 0.f;
#pragma unroll
  for (int i = 0; i < 16; ++i) { v[i] = __expf(v[i] - m); s += v[i]; }
#pragma unroll
  for (int off = 32; off; off >>= 1) s += __shfl_xor(s, off);
  if ((t & 63) == 0) red[4 + (t >> 6)] = s;
  __syncthreads();
  s = (red[4] + red[5]) + (red[6] + red[7]);
  const float inv = 1.0f / s;

  u16x8 o0, o1;
#pragma unroll
  for (int i = 0; i < 8; ++i) o0[i] = f2bf(v[i] * inv);
#pragma unroll
  for (int i = 0; i < 8; ++i) o1[i] = f2bf(v[8 + i] * inv);
  ((u16x8*)p)[t * 2] = o0;
  ((u16x8*)p)[t * 2 + 1] = o1;
}

// -------------------------------------------------------------------------
// S=4096, D_IN=1024, D_OUT=1024.  fp32 in, fp32 out.
// ws layout (bytes): Ebf 8MB | Wt 6MB | QKV 24MB | Vt 8MB | S 32MB = 78MB
// -------------------------------------------------------------------------
extern "C" void kernel_launch(void* const* d_in, const int* in_sizes, int n_in,
                              void* d_out, int out_size, void* d_ws, size_t ws_size,
                              hipStream_t stream) {
  const float* E  = (const float*)d_in[0];
  const float* Wq = (const float*)d_in[1];
  const float* Wk = (const float*)d_in[2];
  const float* Wv = (const float*)d_in[3];
  float* Out = (float*)d_out;

  char* w = (char*)d_ws;
  u16* Ebf = (u16*)(w);
  u16* Wt  = (u16*)(w + (size_t)(8u << 20));
  u16* QKV = (u16*)(w + (size_t)(14u << 20));
  u16* Vt  = (u16*)(w + (size_t)(38u << 20));
  u16* S   = (u16*)(w + (size_t)(46u << 20));

  const dim3 tb(32, 32);

  // zero d_out for the PV split-K atomic accumulation
  zero_f32<<<4096, 256, 0, stream>>>((float4*)Out);

  // stage 0: casts / weight transposes
  cast_f32_bf16<<<4096, 256, 0, stream>>>(E, Ebf);
  transpose_w3<<<dim3(32, 32, 3), tb, 0, stream>>>(Wq, Wk, Wv, Wt);

  // stage 1: QKV = E @ Wt^T   [4096 x 3072], K=1024
  gemm_qkv<<<768, 256, 0, stream>>>(Ebf, Wt, QKV);

  // V^T for the PV GEMM
  transpose_bf16<<<dim3(32, 128), tb, 0, stream>>>(QKV + 2048, 3072, Vt, 4096);

  // stage 2: S = (Q @ K^T) / 32   [4096 x 4096], K=1024
  gemm_score<<<1024, 256, 0, stream>>>(QKV, S);

  // stage 3: P = softmax(S) in place
  softmax_rows<<<4096, 256, 0, stream>>>(S);

  // stage 4: Out = P @ Vt^T  [4096 x 1024], K=4096, split-K=4, atomic epilogue
  gemm_pv<<<dim3(256, 1, 4), 256, 0, stream>>>(S, Vt, Out);
}

// Round 6
// 253.727 us; speedup vs baseline: 1.0386x; 1.0386x over previous
//
#include <hip/hip_runtime.h>
#include <hip/hip_bf16.h>

typedef unsigned short u16;
typedef __bf16 bf16x8 __attribute__((ext_vector_type(8)));
typedef float f32x4 __attribute__((ext_vector_type(4)));
typedef unsigned short u16x8 __attribute__((ext_vector_type(8)));
typedef unsigned short u16x4 __attribute__((ext_vector_type(4)));

__device__ __forceinline__ float bf2f(u16 u) {
  unsigned x = ((unsigned)u) << 16;
  return __builtin_bit_cast(float, x);
}
__device__ __forceinline__ u16 f2bf(float f) {
  unsigned u = __builtin_bit_cast(unsigned, f);
  u += 0x7fffu + ((u >> 16) & 1u);
  return (u16)(u >> 16);
}

// async global -> LDS, 16B per lane; lds base is wave-uniform,
// HW scatters at base + lane*16.
__device__ __forceinline__ void gload16(const u16* g, u16* lds) {
  __builtin_amdgcn_global_load_lds(
      (const __attribute__((address_space(1))) void*)g,
      (__attribute__((address_space(3))) void*)lds,
      16, 0, 0);
}

// -------------------------------------------------------------------------
// C[M,N] = A[M,K] * B[N,K]^T, bf16 row-major, strides lda/ldb.
// 128x128 tile, BK=64, 4 waves x (64x64 per wave, 4x4 MFMA 16x16x32).
// LDS: [128][64] u16 rows, eight 16B chunks XOR-swizzled (slot c ^ (g&7))
// -> conflict-free ds_read_b128 (verified R3: SQ_LDS_BANK_CONFLICT -> 0).
// Block map: by = (b&7) + 8*(b/(8*NX)) -> A-panel sharers on one XCD.
// PIPE=1: classic 2-barrier loop (for kernels with >=3 blocks/CU where
//   implicit cross-block overlap hides the barrier drain).
// PIPE=3: 3-buffer rotation, prefetch depth 2, raw s_barrier + fine
//   s_waitcnt vmcnt(N) (8 loads/tile/wave).  Iter order (R5 race FIXED):
//     waitcnt vmcnt(8|0)  -- own tile-ti loads landed
//     s_barrier           -- all waves' tile-ti loads landed AND all waves'
//                            tile-(ti-1) ds_reads retired (reads precede
//                            each wave's MFMA, which precedes its barrier)
//     stage(ti+2, buf of ti-1)  -- safe overwrite, only after the barrier
//     compute(cur)
//   R5 had stage BEFORE the barrier -> fast wave overwrote a buffer a slow
//   wave was still reading (absmax 1.3e-2).  Steady state: 16 loads/wave
//   outstanding; prefetch covers ~2 compute phases of latency.
// OUT_MODE: 0 = f32 store, 1 = bf16 store (scaled by cscale).
// -------------------------------------------------------------------------
template <int OUT_MODE, int NX, int PIPE>
__device__ __forceinline__ void gemm_body(
    const u16* __restrict__ A, int lda,
    const u16* __restrict__ B, int ldb,
    void* __restrict__ C, int ldc, int K, float cscale)
{
  __shared__ __align__(16) u16 As[PIPE][128 * 64];
  __shared__ __align__(16) u16 Bs[PIPE][128 * 64];

  const int b = blockIdx.x;
  const int by = (b & 7) + 8 * (b / (8 * NX));
  const int bx = (b >> 3) % NX;
  const int m0 = by * 128, n0 = bx * 128;

  const int t = threadIdx.x;
  const int w = t >> 6, l = t & 63;
  const int srow = l >> 3;                   // 0..7 within 8-row group
  const int schunk = ((l & 7) ^ srow) * 8;   // swizzled global chunk (elems)
  const int wm = (w >> 1) * 64, wn = (w & 1) * 64;
  const int fr = l & 15;                     // fragment row
  const int q = l >> 4;                      // quarter-wave 0..3

  f32x4 acc[4][4] = {};

  auto stage = [&](int ti, int buf) {
#pragma unroll
    for (int j = 0; j < 4; ++j) {
      const int rr = 8 * (4 * w + j);        // wave-uniform 8-row group base
      gload16(A + (size_t)(m0 + rr + srow) * lda + ti * 64 + schunk, As[buf] + rr * 64);
      gload16(B + (size_t)(n0 + rr + srow) * ldb + ti * 64 + schunk, Bs[buf] + rr * 64);
    }
  };

  auto compute = [&](int buf) {
#pragma unroll
    for (int s = 0; s < 2; ++s) {            // two K=32 MFMA steps per tile
      const int j = s * 4 + q;               // global 16B chunk index
      bf16x8 af[4], bfr[4];
#pragma unroll
      for (int i = 0; i < 4; ++i) {
        const int ra = wm + 16 * i + fr;
        af[i] = *(const bf16x8*)(As[buf] + ra * 64 + (j ^ (ra & 7)) * 8);
      }
#pragma unroll
      for (int i = 0; i < 4; ++i) {
        const int rb = wn + 16 * i + fr;
        bfr[i] = *(const bf16x8*)(Bs[buf] + rb * 64 + (j ^ (rb & 7)) * 8);
      }
#pragma unroll
      for (int i = 0; i < 4; ++i)
#pragma unroll
        for (int jj = 0; jj < 4; ++jj)
          acc[i][jj] = __builtin_amdgcn_mfma_f32_16x16x32_bf16(af[i], bfr[jj], acc[i][jj], 0, 0, 0);
    }
  };

  if constexpr (PIPE == 1) {
    for (int ti = 0; ti < K / 64; ++ti) {
      __syncthreads();
      stage(ti, 0);
      __syncthreads();
      compute(0);
    }
  } else {
    const int nt = K / 64;
    stage(0, 0);
    stage(1, 1);
    int cur = 0;
    for (int ti = 0; ti < nt; ++ti) {
      if (ti + 1 < nt) {
        __asm__ volatile("s_waitcnt vmcnt(8)" ::: "memory");   // tile ti landed
      } else {
        __asm__ volatile("s_waitcnt vmcnt(0)" ::: "memory");
      }
      __asm__ volatile("s_barrier" ::: "memory");
      if (ti + 2 < nt) {
        int nb = cur + 2; if (nb >= 3) nb -= 3;
        stage(ti + 2, nb);                   // safe: after barrier
      }
      compute(cur);
      ++cur; if (cur == 3) cur = 0;
    }
  }

  // C/D layout (m89-verified): col = lane&15, row = (lane>>4)*4 + reg
  const int er = q * 4;
  const int ec = l & 15;
#pragma unroll
  for (int i = 0; i < 4; ++i)
#pragma unroll
    for (int jj = 0; jj < 4; ++jj)
#pragma unroll
      for (int r = 0; r < 4; ++r) {
        const size_t idx = (size_t)(m0 + wm + 16 * i + er + r) * ldc + (n0 + wn + 16 * jj + ec);
        if (OUT_MODE == 1) ((u16*)C)[idx] = f2bf(acc[i][jj][r] * cscale);
        else               ((float*)C)[idx] = acc[i][jj][r];
      }
}

// distinct names per stage so rocprof separates them
__global__ __launch_bounds__(256) void gemm_qkv(const u16* __restrict__ A,
                                                const u16* __restrict__ B,
                                                u16* __restrict__ C) {
  gemm_body<1, 24, 1>(A, 1024, B, 1024, C, 3072, 1024, 1.0f);
}
__global__ __launch_bounds__(256) void gemm_score(const u16* __restrict__ QKV,
                                                  u16* __restrict__ S) {
  // scale 1/sqrt(1024) folded into the epilogue store
  gemm_body<1, 32, 1>(QKV, 3072, QKV + 1024, 3072, S, 4096, 1024, 0.03125f);
}
__global__ __launch_bounds__(256) void gemm_pv(const u16* __restrict__ S,
                                               const u16* __restrict__ Vt,
                                               float* __restrict__ O) {
  // 1 block/CU -> software-pipelined (PIPE=3, prefetch depth 2)
  gemm_body<0, 8, 3>(S, 4096, Vt, 4096, O, 1024, 4096, 1.0f);
}

// -------------------------------------------------------------------------
// elementwise f32 -> bf16 cast, 4 elems/thread
// -------------------------------------------------------------------------
__global__ __launch_bounds__(256) void cast_f32_bf16(const float* __restrict__ in,
                                                     u16* __restrict__ out) {
  const int i = (blockIdx.x * 256 + threadIdx.x) * 4;
  float4 f = *(const float4*)(in + i);
  u16x4 o;
  o.x = f2bf(f.x); o.y = f2bf(f.y); o.z = f2bf(f.z); o.w = f2bf(f.w);
  *(u16x4*)(out + i) = o;
}

// -------------------------------------------------------------------------
// all three W [1024x1024] f32 -> bf16 transposes in one dispatch (z = which)
// -------------------------------------------------------------------------
__global__ __launch_bounds__(1024) void transpose_w3(
    const float* __restrict__ w0, const float* __restrict__ w1,
    const float* __restrict__ w2, u16* __restrict__ out)
{
  __shared__ u16 tile[32][33];
  const float* in = (blockIdx.z == 0) ? w0 : (blockIdx.z == 1) ? w1 : w2;
  u16* o = out + (size_t)blockIdx.z * 1024 * 1024;
  const int c0 = blockIdx.x * 32, r0 = blockIdx.y * 32;
  const int tx = threadIdx.x, ty = threadIdx.y;
  tile[ty][tx] = f2bf(in[(size_t)(r0 + ty) * 1024 + c0 + tx]);
  __syncthreads();
  o[(size_t)(c0 + ty) * 1024 + r0 + tx] = tile[tx][ty];
}

// -------------------------------------------------------------------------
// bf16 transpose (for V -> V^T): out[c*ldout + r] = in[r*ldin + c]
// -------------------------------------------------------------------------
__global__ __launch_bounds__(1024) void transpose_bf16(
    const u16* __restrict__ in, int ldin, u16* __restrict__ out, int ldout)
{
  __shared__ u16 tile[32][33];
  const int c0 = blockIdx.x * 32, r0 = blockIdx.y * 32;
  const int tx = threadIdx.x, ty = threadIdx.y;
  tile[ty][tx] = in[(size_t)(r0 + ty) * ldin + c0 + tx];
  __syncthreads();
  out[(size_t)(c0 + ty) * ldout + r0 + tx] = tile[tx][ty];
}

// -------------------------------------------------------------------------
// row softmax, in-place on bf16 S[4096][4096] (scale already applied).
// -------------------------------------------------------------------------
__global__ __launch_bounds__(256) void softmax_rows(u16* __restrict__ S) {
  const int N = 4096;
  u16* p = S + (size_t)blockIdx.x * N;
  const int t = threadIdx.x;
  u16x8 u0 = ((const u16x8*)p)[t * 2];
  u16x8 u1 = ((const u16x8*)p)[t * 2 + 1];
  float v[16];
#pragma unroll
  for (int i = 0; i < 8; ++i) v[i] = bf2f(u0[i]);
#pragma unroll
  for (int i = 0; i < 8; ++i) v[8 + i] = bf2f(u1[i]);

  float m = -1e30f;
#pragma unroll
  for (int i = 0; i < 16; ++i) m = fmaxf(m, v[i]);
#pragma unroll
  for (int off = 32; off; off >>= 1) m = fmaxf(m, __shfl_xor(m, off));
  __shared__ float red[8];
  if ((t & 63) == 0) red[t >> 6] = m;
  __syncthreads();
  m = fmaxf(fmaxf(red[0], red[1]), fmaxf(red[2], red[3]));

  float s = 0.f;
#pragma unroll
  for (int i = 0; i < 16; ++i) { v[i] = __expf(v[i] - m); s += v[i]; }
#pragma unroll
  for (int off = 32; off; off >>= 1) s += __shfl_xor(s, off);
  if ((t & 63) == 0) red[4 + (t >> 6)] = s;
  __syncthreads();
  s = (red[4] + red[5]) + (red[6] + red[7]);
  const float inv = 1.0f / s;

  u16x8 o0, o1;
#pragma unroll
  for (int i = 0; i < 8; ++i) o0[i] = f2bf(v[i] * inv);
#pragma unroll
  for (int i = 0; i < 8; ++i) o1[i] = f2bf(v[8 + i] * inv);
  ((u16x8*)p)[t * 2] = o0;
  ((u16x8*)p)[t * 2 + 1] = o1;
}

// -------------------------------------------------------------------------
// S=4096, D_IN=1024, D_OUT=1024.  fp32 in, fp32 out.
// ws layout (bytes): Ebf 8MB | Wt 6MB | QKV 24MB | Vt 8MB | S 32MB = 78MB
// -------------------------------------------------------------------------
extern "C" void kernel_launch(void* const* d_in, const int* in_sizes, int n_in,
                              void* d_out, int out_size, void* d_ws, size_t ws_size,
                              hipStream_t stream) {
  const float* E  = (const float*)d_in[0];
  const float* Wq = (const float*)d_in[1];
  const float* Wk = (const float*)d_in[2];
  const float* Wv = (const float*)d_in[3];
  float* Out = (float*)d_out;

  char* w = (char*)d_ws;
  u16* Ebf = (u16*)(w);
  u16* Wt  = (u16*)(w + (size_t)(8u << 20));
  u16* QKV = (u16*)(w + (size_t)(14u << 20));
  u16* Vt  = (u16*)(w + (size_t)(38u << 20));
  u16* S   = (u16*)(w + (size_t)(46u << 20));

  const dim3 tb(32, 32);

  // stage 0: casts / weight transposes
  cast_f32_bf16<<<4096, 256, 0, stream>>>(E, Ebf);
  transpose_w3<<<dim3(32, 32, 3), tb, 0, stream>>>(Wq, Wk, Wv, Wt);

  // stage 1: QKV = E @ Wt^T   [4096 x 3072], K=1024
  gemm_qkv<<<768, 256, 0, stream>>>(Ebf, Wt, QKV);

  // V^T for the PV GEMM
  transpose_bf16<<<dim3(32, 128), tb, 0, stream>>>(QKV + 2048, 3072, Vt, 4096);

  // stage 2: S = (Q @ K^T) / 32   [4096 x 4096], K=1024
  gemm_score<<<1024, 256, 0, stream>>>(QKV, S);

  // stage 3: P = softmax(S) in place
  softmax_rows<<<4096, 256, 0, stream>>>(S);

  // stage 4: Out = P @ Vt^T  [4096 x 1024], K=4096, pipelined
  gemm_pv<<<256, 256, 0, stream>>>(S, Vt, Out);
}

// Round 7
// 237.102 us; speedup vs baseline: 1.1115x; 1.0701x over previous
//
#include <hip/hip_runtime.h>
#include <hip/hip_bf16.h>

typedef unsigned short u16;
typedef __bf16 bf16x8 __attribute__((ext_vector_type(8)));
typedef float f32x4 __attribute__((ext_vector_type(4)));
typedef unsigned short u16x8 __attribute__((ext_vector_type(8)));
typedef unsigned short u16x4 __attribute__((ext_vector_type(4)));

__device__ __forceinline__ float bf2f(u16 u) {
  unsigned x = ((unsigned)u) << 16;
  return __builtin_bit_cast(float, x);
}
__device__ __forceinline__ u16 f2bf(float f) {
  unsigned u = __builtin_bit_cast(unsigned, f);
  u += 0x7fffu + ((u >> 16) & 1u);
  return (u16)(u >> 16);
}

// async global -> LDS, 16B per lane; lds base is wave-uniform,
// HW scatters at base + lane*16.
__device__ __forceinline__ void gload16(const u16* g, u16* lds) {
  __builtin_amdgcn_global_load_lds(
      (const __attribute__((address_space(1))) void*)g,
      (__attribute__((address_space(3))) void*)lds,
      16, 0, 0);
}

// -------------------------------------------------------------------------
// C[M,N] = A[M,K] * B[N,K]^T, bf16 row-major, strides lda/ldb.
// 128x128 tile, BK in {64,128}, 4 waves x (64x64 per wave, 4x4 MFMA
// 16x16x32).  LDS: [128][BK] u16 rows; each row's 16B chunks XOR-swizzled
// (slot c ^ (row&7)) -> conflict-free ds_read_b128 (R3: 4.2M -> 0) while
// keeping the global_load_lds lane scatter contiguous (we permute the
// *global* address per lane, chunk = c ^ (row&7); row stride is a multiple
// of 128B so bank group = 4*(chunk&7), XOR spans all 8 groups).
// Block map: by = (b&7) + 8*(b/(8*NX)) -> A-panel sharers on one XCD.
// K-loop: plain 2-barrier structure.  R4-R6 established: split-K atomics
// regress (write-through + coherence cost), and source-level vmcnt
// pipelining is defeated by the compiler (m131/m135).  For the 1-block/CU
// PV kernel the per-iter load-drain stall is ~fixed, so PV uses BK=128
// (64 KB LDS, free at 1 block/CU) to halve the number of stalls; qkv/score
// (3-4 blocks/CU) keep BK=64 so occupancy-based overlap keeps working
// (m132: 64 KB LDS costs a resident block there).
// OUT_MODE: 0 = f32 store, 1 = bf16 store (scaled by cscale).
// -------------------------------------------------------------------------
template <int OUT_MODE, int NX, int BK>
__device__ __forceinline__ void gemm_body(
    const u16* __restrict__ A, int lda,
    const u16* __restrict__ B, int ldb,
    void* __restrict__ C, int ldc, int K, float cscale)
{
  __shared__ __align__(16) u16 As[128 * BK];
  __shared__ __align__(16) u16 Bs[128 * BK];

  constexpr int CPR = BK / 8;    // 16B chunks per row: 8 (BK=64) / 16 (BK=128)
  constexpr int RPG = 512 / BK;  // rows per gload16: 8 / 4
  constexpr int IPW = 32 / RPG;  // gload16 per operand per wave: 4 / 8

  const int b = blockIdx.x;
  const int by = (b & 7) + 8 * (b / (8 * NX));
  const int bx = (b >> 3) % NX;
  const int m0 = by * 128, n0 = bx * 128;

  const int t = threadIdx.x;
  const int w = t >> 6, l = t & 63;
  const int srow = l / CPR;                  // staging row within group
  const int lc = l % CPR;                    // staging chunk slot within row
  const int wm = (w >> 1) * 64, wn = (w & 1) * 64;
  const int fr = l & 15;                     // fragment row
  const int q = l >> 4;                      // quarter-wave 0..3

  f32x4 acc[4][4] = {};

  for (int kt = 0; kt < K; kt += BK) {
    __syncthreads();
#pragma unroll
    for (int j = 0; j < IPW; ++j) {
      const int rr = RPG * (IPW * w + j);    // wave-uniform row-group base
      const int ga = rr + srow;              // tile row this lane feeds
      const int sch = ((lc ^ (ga & 7))) * 8; // swizzled global chunk (elems)
      gload16(A + (size_t)(m0 + ga) * lda + kt + sch, As + rr * BK);
      gload16(B + (size_t)(n0 + ga) * ldb + kt + sch, Bs + rr * BK);
    }
    __syncthreads();

#pragma unroll
    for (int s = 0; s < BK / 32; ++s) {      // K=32 MFMA steps per tile
      const int j = s * 4 + q;               // global 16B chunk index
      bf16x8 af[4], bfr[4];
#pragma unroll
      for (int i = 0; i < 4; ++i) {
        const int ra = wm + 16 * i + fr;
        af[i] = *(const bf16x8*)(As + ra * BK + (j ^ (ra & 7)) * 8);
      }
#pragma unroll
      for (int i = 0; i < 4; ++i) {
        const int rb = wn + 16 * i + fr;
        bfr[i] = *(const bf16x8*)(Bs + rb * BK + (j ^ (rb & 7)) * 8);
      }
#pragma unroll
      for (int i = 0; i < 4; ++i)
#pragma unroll
        for (int jj = 0; jj < 4; ++jj)
          acc[i][jj] = __builtin_amdgcn_mfma_f32_16x16x32_bf16(af[i], bfr[jj], acc[i][jj], 0, 0, 0);
    }
  }

  // C/D layout (m89-verified): col = lane&15, row = (lane>>4)*4 + reg
  const int er = q * 4;
  const int ec = l & 15;
#pragma unroll
  for (int i = 0; i < 4; ++i)
#pragma unroll
    for (int jj = 0; jj < 4; ++jj)
#pragma unroll
      for (int r = 0; r < 4; ++r) {
        const size_t idx = (size_t)(m0 + wm + 16 * i + er + r) * ldc + (n0 + wn + 16 * jj + ec);
        if (OUT_MODE == 1) ((u16*)C)[idx] = f2bf(acc[i][jj][r] * cscale);
        else               ((float*)C)[idx] = acc[i][jj][r];
      }
}

// distinct names per stage so rocprof separates them
__global__ __launch_bounds__(256) void gemm_qkv(const u16* __restrict__ A,
                                                const u16* __restrict__ B,
                                                u16* __restrict__ C) {
  gemm_body<1, 24, 64>(A, 1024, B, 1024, C, 3072, 1024, 1.0f);
}
__global__ __launch_bounds__(256) void gemm_score(const u16* __restrict__ QKV,
                                                  u16* __restrict__ S) {
  // scale 1/sqrt(1024) folded into the epilogue store
  gemm_body<1, 32, 64>(QKV, 3072, QKV + 1024, 3072, S, 4096, 1024, 0.03125f);
}
__global__ __launch_bounds__(256) void gemm_pv(const u16* __restrict__ S,
                                               const u16* __restrict__ Vt,
                                               float* __restrict__ O) {
  // 1 block/CU -> BK=128 (64 KB LDS) halves the per-iter stall count
  gemm_body<0, 8, 128>(S, 4096, Vt, 4096, O, 1024, 4096, 1.0f);
}

// -------------------------------------------------------------------------
// elementwise f32 -> bf16 cast, 4 elems/thread
// -------------------------------------------------------------------------
__global__ __launch_bounds__(256) void cast_f32_bf16(const float* __restrict__ in,
                                                     u16* __restrict__ out) {
  const int i = (blockIdx.x * 256 + threadIdx.x) * 4;
  float4 f = *(const float4*)(in + i);
  u16x4 o;
  o.x = f2bf(f.x); o.y = f2bf(f.y); o.z = f2bf(f.z); o.w = f2bf(f.w);
  *(u16x4*)(out + i) = o;
}

// -------------------------------------------------------------------------
// all three W [1024x1024] f32 -> bf16 transposes in one dispatch (z = which)
// -------------------------------------------------------------------------
__global__ __launch_bounds__(1024) void transpose_w3(
    const float* __restrict__ w0, const float* __restrict__ w1,
    const float* __restrict__ w2, u16* __restrict__ out)
{
  __shared__ u16 tile[32][33];
  const float* in = (blockIdx.z == 0) ? w0 : (blockIdx.z == 1) ? w1 : w2;
  u16* o = out + (size_t)blockIdx.z * 1024 * 1024;
  const int c0 = blockIdx.x * 32, r0 = blockIdx.y * 32;
  const int tx = threadIdx.x, ty = threadIdx.y;
  tile[ty][tx] = f2bf(in[(size_t)(r0 + ty) * 1024 + c0 + tx]);
  __syncthreads();
  o[(size_t)(c0 + ty) * 1024 + r0 + tx] = tile[tx][ty];
}

// -------------------------------------------------------------------------
// bf16 transpose (for V -> V^T): out[c*ldout + r] = in[r*ldin + c]
// -------------------------------------------------------------------------
__global__ __launch_bounds__(1024) void transpose_bf16(
    const u16* __restrict__ in, int ldin, u16* __restrict__ out, int ldout)
{
  __shared__ u16 tile[32][33];
  const int c0 = blockIdx.x * 32, r0 = blockIdx.y * 32;
  const int tx = threadIdx.x, ty = threadIdx.y;
  tile[ty][tx] = in[(size_t)(r0 + ty) * ldin + c0 + tx];
  __syncthreads();
  out[(size_t)(c0 + ty) * ldout + r0 + tx] = tile[tx][ty];
}

// -------------------------------------------------------------------------
// row softmax, in-place on bf16 S[4096][4096] (scale already applied).
// -------------------------------------------------------------------------
__global__ __launch_bounds__(256) void softmax_rows(u16* __restrict__ S) {
  const int N = 4096;
  u16* p = S + (size_t)blockIdx.x * N;
  const int t = threadIdx.x;
  u16x8 u0 = ((const u16x8*)p)[t * 2];
  u16x8 u1 = ((const u16x8*)p)[t * 2 + 1];
  float v[16];
#pragma unroll
  for (int i = 0; i < 8; ++i) v[i] = bf2f(u0[i]);
#pragma unroll
  for (int i = 0; i < 8; ++i) v[8 + i] = bf2f(u1[i]);

  float m = -1e30f;
#pragma unroll
  for (int i = 0; i < 16; ++i) m = fmaxf(m, v[i]);
#pragma unroll
  for (int off = 32; off; off >>= 1) m = fmaxf(m, __shfl_xor(m, off));
  __shared__ float red[8];
  if ((t & 63) == 0) red[t >> 6] = m;
  __syncthreads();
  m = fmaxf(fmaxf(red[0], red[1]), fmaxf(red[2], red[3]));

  float s = 0.f;
#pragma unroll
  for (int i = 0; i < 16; ++i) { v[i] = __expf(v[i] - m); s += v[i]; }
#pragma unroll
  for (int off = 32; off; off >>= 1) s += __shfl_xor(s, off);
  if ((t & 63) == 0) red[4 + (t >> 6)] = s;
  __syncthreads();
  s = (red[4] + red[5]) + (red[6] + red[7]);
  const float inv = 1.0f / s;

  u16x8 o0, o1;
#pragma unroll
  for (int i = 0; i < 8; ++i) o0[i] = f2bf(v[i] * inv);
#pragma unroll
  for (int i = 0; i < 8; ++i) o1[i] = f2bf(v[8 + i] * inv);
  ((u16x8*)p)[t * 2] = o0;
  ((u16x8*)p)[t * 2 + 1] = o1;
}

// -------------------------------------------------------------------------
// S=4096, D_IN=1024, D_OUT=1024.  fp32 in, fp32 out.
// ws layout (bytes): Ebf 8MB | Wt 6MB | QKV 24MB | Vt 8MB | S 32MB = 78MB
// -------------------------------------------------------------------------
extern "C" void kernel_launch(void* const* d_in, const int* in_sizes, int n_in,
                              void* d_out, int out_size, void* d_ws, size_t ws_size,
                              hipStream_t stream) {
  const float* E  = (const float*)d_in[0];
  const float* Wq = (const float*)d_in[1];
  const float* Wk = (const float*)d_in[2];
  const float* Wv = (const float*)d_in[3];
  float* Out = (float*)d_out;

  char* w = (char*)d_ws;
  u16* Ebf = (u16*)(w);
  u16* Wt  = (u16*)(w + (size_t)(8u << 20));
  u16* QKV = (u16*)(w + (size_t)(14u << 20));
  u16* Vt  = (u16*)(w + (size_t)(38u << 20));
  u16* S   = (u16*)(w + (size_t)(46u << 20));

  const dim3 tb(32, 32);

  // stage 0: casts / weight transposes
  cast_f32_bf16<<<4096, 256, 0, stream>>>(E, Ebf);
  transpose_w3<<<dim3(32, 32, 3), tb, 0, stream>>>(Wq, Wk, Wv, Wt);

  // stage 1: QKV = E @ Wt^T   [4096 x 3072], K=1024
  gemm_qkv<<<768, 256, 0, stream>>>(Ebf, Wt, QKV);

  // V^T for the PV GEMM
  transpose_bf16<<<dim3(32, 128), tb, 0, stream>>>(QKV + 2048, 3072, Vt, 4096);

  // stage 2: S = (Q @ K^T) / 32   [4096 x 4096], K=1024
  gemm_score<<<1024, 256, 0, stream>>>(QKV, S);

  // stage 3: P = softmax(S) in place
  softmax_rows<<<4096, 256, 0, stream>>>(S);

  // stage 4: Out = P @ Vt^T  [4096 x 1024], K=4096, BK=128
  gemm_pv<<<256, 256, 0, stream>>>(S, Vt, Out);
}